// Round 6
// baseline (380.347 us; speedup 1.0000x reference)
//
#include <hip/hip_runtime.h>
#include <hip/hip_bf16.h>

#define NROWS 16384
#define NCODES 8192
#define DIM 256
#define BM 128                     // rows per block
#define CPB 1024                   // codes per block (8-way split, XCD-aligned)
#define CAP 16
#define MARGIN 3.0e-4f

typedef __attribute__((ext_vector_type(8))) short bf16x8;
typedef __attribute__((ext_vector_type(4))) float f32x4;

__device__ inline unsigned short f2bf(float f) {
    union { __hip_bfloat16 h; unsigned short u; } cv;
    cv.h = __float2bfloat16(f);
    return cv.u;
}
__device__ inline unsigned f2ord(float f) {
    unsigned u = __float_as_uint(f);
    return u ^ ((u >> 31) ? 0xFFFFFFFFu : 0x80000000u);
}
__device__ inline float ord2f(unsigned u) {
    unsigned v = (u & 0x80000000u) ? (u ^ 0x80000000u) : ~u;
    return __uint_as_float(v);
}

// EXACT numpy pairwise sum-of-squares for a 256-vector (validated round 2).
__device__ float pairwise256_sq(const float4* p) {
    float res[2];
    #pragma unroll
    for (int h = 0; h < 2; ++h) {
        float r[8];
        #pragma unroll
        for (int j = 0; j < 8; ++j) r[j] = 0.0f;
        #pragma unroll
        for (int g = 0; g < 16; ++g) {
            float4 v0 = p[h * 32 + g * 2];
            float4 v1 = p[h * 32 + g * 2 + 1];
            r[0] = __fadd_rn(r[0], __fmul_rn(v0.x, v0.x));
            r[1] = __fadd_rn(r[1], __fmul_rn(v0.y, v0.y));
            r[2] = __fadd_rn(r[2], __fmul_rn(v0.z, v0.z));
            r[3] = __fadd_rn(r[3], __fmul_rn(v0.w, v0.w));
            r[4] = __fadd_rn(r[4], __fmul_rn(v1.x, v1.x));
            r[5] = __fadd_rn(r[5], __fmul_rn(v1.y, v1.y));
            r[6] = __fadd_rn(r[6], __fmul_rn(v1.z, v1.z));
            r[7] = __fadd_rn(r[7], __fmul_rn(v1.w, v1.w));
        }
        res[h] = __fadd_rn(__fadd_rn(__fadd_rn(r[0], r[1]), __fadd_rn(r[2], r[3])),
                           __fadd_rn(__fadd_rn(r[4], r[5]), __fadd_rn(r[6], r[7])));
    }
    return __fadd_rn(res[0], res[1]);
}

// Fused prep: wfrag swizzle + xsq + wsq + best64g init (one launch).
// wfrag: flat unit u = (k32*512 + c16)*64 + L holds 8 bf16 =
//   W[c16*16 + (L&15)][k32*32 + (L>>4)*8 + j]
#define WFRAG_UNITS (NCODES * DIM / 8)   // 262144
__global__ __launch_bounds__(256)
void prep_kernel(const float* __restrict__ x, const float* __restrict__ w,
                 unsigned short* __restrict__ whf, float* __restrict__ xsq,
                 float* __restrict__ wsq, unsigned long long* __restrict__ best64g) {
    int gid = blockIdx.x * 256 + threadIdx.x;
    if (gid < WFRAG_UNITS) {
        int L = gid & 63;
        int rest = gid >> 6;
        int c16 = rest & 511;
        int k32 = rest >> 9;
        int code = c16 * 16 + (L & 15);
        int k = k32 * 32 + (L >> 4) * 8;
        const float4* p = reinterpret_cast<const float4*>(w + (size_t)code * DIM + k);
        float4 u0 = p[0], u1 = p[1];
        unsigned short tmp[8];
        tmp[0] = f2bf(u0.x); tmp[1] = f2bf(u0.y); tmp[2] = f2bf(u0.z); tmp[3] = f2bf(u0.w);
        tmp[4] = f2bf(u1.x); tmp[5] = f2bf(u1.y); tmp[6] = f2bf(u1.z); tmp[7] = f2bf(u1.w);
        *reinterpret_cast<uint4*>(whf + (size_t)gid * 8) = *reinterpret_cast<uint4*>(tmp);
    } else {
        int t = gid - WFRAG_UNITS;
        if (t < NROWS) {
            xsq[t] = pairwise256_sq(reinterpret_cast<const float4*>(x + (size_t)t * DIM));
            best64g[t] = ~0ull;
        } else if (t < NROWS + NCODES) {
            int c = t - NROWS;
            wsq[c] = pairwise256_sq(reinterpret_cast<const float4*>(w + (size_t)c * DIM));
        }
    }
}

// Main: 512 thr (8 waves), A-tile in LDS, B global->reg (L2-resident per XCD),
// barrier-free K-loop, cross-pass B prefetch.
__global__ __launch_bounds__(512, 2)
void vq_main(const float* __restrict__ x, const float* __restrict__ w,
             const unsigned short* __restrict__ whf,
             const float* __restrict__ wsq, const float* __restrict__ xsq,
             unsigned long long* __restrict__ best64g) {
    __shared__ unsigned short afrag[8 * 8 * 64 * 8];   // rg,k32,lane -> 16B frag; 64 KB
    __shared__ unsigned rowmin[BM];
    __shared__ int cnt[BM];
    __shared__ int cand[BM][CAP];

    const int tid = threadIdx.x;
    const int lane = tid & 63;
    const int wv = tid >> 6;          // 0..7
    const int lm = lane & 15;
    const int lq = lane >> 4;

    // 8-way split keyed to XCD (blk%8): per-XCD B working set = 512 KB (L2-resident)
    const int blk = blockIdx.x;
    const int split = blk & 7;
    const int rowBase = (blk >> 3) * BM;
    // wave's 128 codes: base c16 = split*64 + wv*8; pass p covers +p*4 .. +p*4+3
    const int wave16 = split * 64 + wv * 8;

    if (tid < BM) { rowmin[tid] = 0xFFFFFFFFu; cnt[tid] = 0; }

    // ---- stage A tile once (bf16, fragment order); wave wv handles rg=wv ----
    {
        const int rg = wv;
        const float* xr = x + (size_t)(rowBase + rg * 16 + lm) * DIM + lq * 8;
        #pragma unroll
        for (int k32 = 0; k32 < 8; ++k32) {
            float4 u0 = *reinterpret_cast<const float4*>(xr + k32 * 32);
            float4 u1 = *reinterpret_cast<const float4*>(xr + k32 * 32 + 4);
            unsigned short t8[8];
            t8[0] = f2bf(u0.x); t8[1] = f2bf(u0.y); t8[2] = f2bf(u0.z); t8[3] = f2bf(u0.w);
            t8[4] = f2bf(u1.x); t8[5] = f2bf(u1.y); t8[6] = f2bf(u1.z); t8[7] = f2bf(u1.w);
            *reinterpret_cast<uint4*>(afrag + ((rg * 8 + k32) * 64 + lane) * 8) =
                *reinterpret_cast<uint4*>(t8);
        }
    }
    __syncthreads();   // the ONLY barrier before the final reduction

    bf16x8 bb[2][4];
    #pragma unroll
    for (int cf = 0; cf < 4; ++cf)
        bb[0][cf] = *reinterpret_cast<const bf16x8*>(
            whf + (((size_t)(wave16 + cf)) * 64 + lane) * 8);

    #pragma unroll
    for (int p = 0; p < 2; ++p) {                       // 2 passes x 64 codes
        const int pbase16 = wave16 + p * 4;
        f32x4 acc[8][4];
        #pragma unroll
        for (int rg = 0; rg < 8; ++rg)
            #pragma unroll
            for (int cf = 0; cf < 4; ++cf)
                acc[rg][cf] = (f32x4){0.f, 0.f, 0.f, 0.f};

        #pragma unroll
        for (int k32 = 0; k32 < 8; ++k32) {
            const int cur = k32 & 1;
            if (k32 < 7) {
                #pragma unroll
                for (int cf = 0; cf < 4; ++cf)
                    bb[cur ^ 1][cf] = *reinterpret_cast<const bf16x8*>(
                        whf + (((size_t)((k32 + 1) * 512 + pbase16 + cf)) * 64 + lane) * 8);
            } else if (p == 0) {
                // cross-pass prefetch: next pass's k32=0 buffer, hidden by score phase
                #pragma unroll
                for (int cf = 0; cf < 4; ++cf)
                    bb[cur ^ 1][cf] = *reinterpret_cast<const bf16x8*>(
                        whf + (((size_t)(pbase16 + 4 + cf)) * 64 + lane) * 8);
            }
            bf16x8 a[8];
            #pragma unroll
            for (int rg = 0; rg < 8; ++rg)
                a[rg] = *reinterpret_cast<const bf16x8*>(
                    afrag + ((rg * 8 + k32) * 64 + lane) * 8);
            #pragma unroll
            for (int cf = 0; cf < 4; ++cf)
                #pragma unroll
                for (int rg = 0; rg < 8; ++rg)
                    acc[rg][cf] = __builtin_amdgcn_mfma_f32_16x16x32_bf16(
                        a[rg], bb[cur][cf], acc[rg][cf], 0, 0, 0);
        }
        // after pass 0's loop, bb[0] already holds pass 1's first buffer

        // ---- approx score: s = wsq - 2*dot ----
        float wq[4];
        #pragma unroll
        for (int cf = 0; cf < 4; ++cf)
            wq[cf] = wsq[(pbase16 + cf) * 16 + lm];

        float mloc[32];
        #pragma unroll
        for (int rg = 0; rg < 8; ++rg) {
            #pragma unroll
            for (int r = 0; r < 4; ++r) {
                float m = __builtin_huge_valf();
                #pragma unroll
                for (int cf = 0; cf < 4; ++cf)
                    m = fminf(m, fmaf(-2.f, acc[rg][cf][r], wq[cf]));
                mloc[rg * 4 + r] = m;
                float rm = m;
                rm = fminf(rm, __shfl_xor(rm, 1, 64));
                rm = fminf(rm, __shfl_xor(rm, 2, 64));
                rm = fminf(rm, __shfl_xor(rm, 4, 64));
                rm = fminf(rm, __shfl_xor(rm, 8, 64));
                if (lm == 0)
                    atomicMin(&rowmin[rg * 16 + lq * 4 + r], f2ord(rm));
            }
        }
        // collect candidates vs prefix min (stale rowmin => superset, safe)
        #pragma unroll
        for (int rg = 0; rg < 8; ++rg) {
            #pragma unroll
            for (int r = 0; r < 4; ++r) {
                const int row = rg * 16 + lq * 4 + r;
                float limit = ord2f(rowmin[row]) + MARGIN;
                if (mloc[rg * 4 + r] <= limit) {
                    #pragma unroll
                    for (int cf = 0; cf < 4; ++cf) {
                        float s = fmaf(-2.f, acc[rg][cf][r], wq[cf]);
                        if (s <= limit) {
                            int pos = atomicAdd(&cnt[row], 1);
                            if (pos < CAP)
                                cand[row][pos] = (pbase16 + cf) * 16 + lm;
                        }
                    }
                }
            }
        }
    }
    __syncthreads();

    // ---- exact rescore (bit-identical to round-2 validated formula) ----
    for (int slot = tid; slot < BM * CAP; slot += 512) {
        int row = slot / CAP, pos = slot - (slot / CAP) * CAP;
        int n = cnt[row] < CAP ? cnt[row] : CAP;
        if (pos < n) {
            int c = cand[row][pos];
            const float* xr = x + (size_t)(rowBase + row) * DIM;
            const float* wr = w + (size_t)c * DIM;
            float d = 0.f;
            for (int k = 0; k < DIM; k += 4) {
                float4 a = *reinterpret_cast<const float4*>(xr + k);
                float4 b = *reinterpret_cast<const float4*>(wr + k);
                d = fmaf(a.x, b.x, d);
                d = fmaf(a.y, b.y, d);
                d = fmaf(a.z, b.z, d);
                d = fmaf(a.w, b.w, d);
            }
            float t1 = __fadd_rn(xsq[rowBase + row], wsq[c]);
            float s = __fsub_rn(t1, __fadd_rn(d, d));
            unsigned long long key =
                ((unsigned long long)__float_as_uint(s) << 32) | (unsigned)c;
            atomicMin(best64g + rowBase + row, key);   // s>0: bit order = float order
        }
    }
}

// Final: read per-row best key, write index + gather codeword.
__global__ __launch_bounds__(256)
void out_kernel(const float* __restrict__ w,
                const unsigned long long* __restrict__ best64g,
                float* __restrict__ out_q, float* __restrict__ out_idx) {
    int r = blockIdx.x * 4 + (threadIdx.x >> 6);
    int lane = threadIdx.x & 63;
    unsigned long long key = best64g[r];
    int idx = (int)(key & 0xFFFFFFFFu);
    float4 v = reinterpret_cast<const float4*>(w + (size_t)idx * DIM)[lane];
    reinterpret_cast<float4*>(out_q + (size_t)r * DIM)[lane] = v;
    if (lane == 0) out_idx[r] = (float)idx;
}

extern "C" void kernel_launch(void* const* d_in, const int* in_sizes, int n_in,
                              void* d_out, int out_size, void* d_ws, size_t ws_size,
                              hipStream_t stream) {
    const float* x = (const float*)d_in[0];   // (16384, 256) fp32
    const float* w = (const float*)d_in[1];   // (8192, 256) fp32
    float* out_q = (float*)d_out;
    float* out_idx = (float*)d_out + (size_t)NROWS * DIM;

    unsigned short* whf = (unsigned short*)d_ws;                      // 4 MB
    float* wsq = (float*)((char*)d_ws + (size_t)NCODES * DIM * 2);    // 32 KB
    float* xsq = wsq + NCODES;                                        // 64 KB
    unsigned long long* best64g = (unsigned long long*)(xsq + NROWS); // 128 KB

    prep_kernel<<<(WFRAG_UNITS + NROWS + NCODES) / 256, 256, 0, stream>>>(
        x, w, whf, xsq, wsq, best64g);
    vq_main<<<(NROWS / BM) * 8, 512, 0, stream>>>(x, w, whf, wsq, xsq, best64g);
    out_kernel<<<NROWS / 4, 256, 0, stream>>>(w, best64g, out_q, out_idx);
}

// Round 9
// 336.033 us; speedup vs baseline: 1.1319x; 1.1319x over previous
//
#include <hip/hip_runtime.h>

#define NROWS 16384
#define NCODES 8192
#define DIM 256
#define BM 64                      // rows per block; grid 256 = 1 block/CU
#define CAP 48
#define MARGIN 1.2e-3f
#define WSCALE 8192.0f             // exact power of two: w' = w * 8192 in [-1,1]

typedef __attribute__((ext_vector_type(4))) float f32x4;

// HW fp8 e4m3fn conversion (RNE, saturating): packs 2 floats -> 2 fp8 bytes.
__device__ inline unsigned cvt2fp8(float a, float b) {
    return (unsigned)__builtin_amdgcn_cvt_pk_fp8_f32(a, b, 0, false) & 0xFFFFu;
}
__device__ inline unsigned long long pack8fp8(float4 u0, float4 u1) {
    unsigned lo = cvt2fp8(u0.x, u0.y) | (cvt2fp8(u0.z, u0.w) << 16);
    unsigned hi = cvt2fp8(u1.x, u1.y) | (cvt2fp8(u1.z, u1.w) << 16);
    return (unsigned long long)lo | ((unsigned long long)hi << 32);
}
__device__ inline unsigned f2ord(float f) {
    unsigned u = __float_as_uint(f);
    return u ^ ((u >> 31) ? 0xFFFFFFFFu : 0x80000000u);
}
__device__ inline float ord2f(unsigned u) {
    unsigned v = (u & 0x80000000u) ? (u ^ 0x80000000u) : ~u;
    return __uint_as_float(v);
}

// EXACT numpy pairwise sum-of-squares for a 256-vector (validated round 2).
__device__ float pairwise256_sq(const float4* p) {
    float res[2];
    #pragma unroll
    for (int h = 0; h < 2; ++h) {
        float r[8];
        #pragma unroll
        for (int j = 0; j < 8; ++j) r[j] = 0.0f;
        #pragma unroll
        for (int g = 0; g < 16; ++g) {
            float4 v0 = p[h * 32 + g * 2];
            float4 v1 = p[h * 32 + g * 2 + 1];
            r[0] = __fadd_rn(r[0], __fmul_rn(v0.x, v0.x));
            r[1] = __fadd_rn(r[1], __fmul_rn(v0.y, v0.y));
            r[2] = __fadd_rn(r[2], __fmul_rn(v0.z, v0.z));
            r[3] = __fadd_rn(r[3], __fmul_rn(v0.w, v0.w));
            r[4] = __fadd_rn(r[4], __fmul_rn(v1.x, v1.x));
            r[5] = __fadd_rn(r[5], __fmul_rn(v1.y, v1.y));
            r[6] = __fadd_rn(r[6], __fmul_rn(v1.z, v1.z));
            r[7] = __fadd_rn(r[7], __fmul_rn(v1.w, v1.w));
        }
        res[h] = __fadd_rn(__fadd_rn(__fadd_rn(r[0], r[1]), __fadd_rn(r[2], r[3])),
                           __fadd_rn(__fadd_rn(r[4], r[5]), __fadd_rn(r[6], r[7])));
    }
    return __fadd_rn(res[0], res[1]);
}

// Bit-exact rescore (round-2 validated formula), x-row from LDS copy (same bits).
__device__ __attribute__((noinline))
void rescore_one(const float* xrow_lds, const float* __restrict__ w,
                 const float* __restrict__ wsq, float xsqv, int rowglob, int c,
                 unsigned long long* __restrict__ best64g) {
    const float* wr = w + (size_t)c * DIM;
    float d = 0.f;
    for (int k = 0; k < DIM; k += 4) {
        float4 a = *reinterpret_cast<const float4*>(xrow_lds + k);
        float4 b = *reinterpret_cast<const float4*>(wr + k);
        d = fmaf(a.x, b.x, d);
        d = fmaf(a.y, b.y, d);
        d = fmaf(a.z, b.z, d);
        d = fmaf(a.w, b.w, d);
    }
    float t1 = __fadd_rn(xsqv, wsq[c]);
    float s = __fsub_rn(t1, __fadd_rn(d, d));
    unsigned long long key =
        ((unsigned long long)__float_as_uint(s) << 32) | (unsigned)c;
    atomicMin(best64g + rowglob, key);   // s>0: bit order = float order; lex (s, idx)
}

// Fused prep: fp8 W-fragment swizzle (scaled x8192) + xsq + wsq + best64g init.
// whf64 unit u = (k32*512 + c16)*64 + L holds 8 fp8 =
//   Wscaled[c16*16 + (L&15)][k32*32 + (L>>4)*8 + j], j=0..7
#define WFRAG_UNITS (NCODES * DIM / 8)   // 262144 (8-byte units, 2 MB total)
__global__ __launch_bounds__(256)
void prep_kernel(const float* __restrict__ x, const float* __restrict__ w,
                 unsigned long long* __restrict__ whf64, float* __restrict__ xsq,
                 float* __restrict__ wsq, unsigned long long* __restrict__ best64g) {
    int gid = blockIdx.x * 256 + threadIdx.x;
    if (gid < WFRAG_UNITS) {
        int L = gid & 63;
        int rest = gid >> 6;
        int c16 = rest & 511;
        int k32 = rest >> 9;
        int code = c16 * 16 + (L & 15);
        int k = k32 * 32 + (L >> 4) * 8;
        const float4* p = reinterpret_cast<const float4*>(w + (size_t)code * DIM + k);
        float4 u0 = p[0], u1 = p[1];
        u0.x *= WSCALE; u0.y *= WSCALE; u0.z *= WSCALE; u0.w *= WSCALE;
        u1.x *= WSCALE; u1.y *= WSCALE; u1.z *= WSCALE; u1.w *= WSCALE;
        whf64[gid] = pack8fp8(u0, u1);
    } else {
        int t = gid - WFRAG_UNITS;
        if (t < NROWS) {
            xsq[t] = pairwise256_sq(reinterpret_cast<const float4*>(x + (size_t)t * DIM));
            best64g[t] = ~0ull;
        } else if (t < NROWS + NCODES) {
            int c = t - NROWS;
            wsq[c] = pairwise256_sq(reinterpret_cast<const float4*>(w + (size_t)c * DIM));
        }
    }
}

// Main: grid 256 (1/CU), 512 thr (8 waves). No code split: x read once.
// x-tile fp32 in LDS (A-pack + rescores); A fp8 in regs; B fp8 from global
// (2 MB, L2-resident), 4-deep register pipeline; no K-loop barriers.
__global__ __launch_bounds__(512, 2)
void vq_main(const float* __restrict__ x, const float* __restrict__ w,
             const unsigned long long* __restrict__ whf64,
             const float* __restrict__ wsq, const float* __restrict__ xsq,
             unsigned long long* __restrict__ best64g) {
    __shared__ float xtile[BM][DIM];          // 64 KB fp32 x rows
    __shared__ unsigned rowmin[BM];
    __shared__ int cnt[BM];
    __shared__ int candc[BM][CAP];
    __shared__ float cands[BM][CAP];

    const int tid = threadIdx.x;
    const int lane = tid & 63;
    const int wv = tid >> 6;          // 0..7: wave owns codes [wv*1024, wv*1024+1023]
    const int lm = lane & 15;
    const int lq = lane >> 4;
    const int rowBase = blockIdx.x * BM;
    const int wave16 = wv * 64;       // base c16 for this wave

    if (tid < BM) { rowmin[tid] = 0xFFFFFFFFu; cnt[tid] = 0; }

    // ---- stage x tile (fp32) into LDS, coalesced ----
    #pragma unroll
    for (int it = 0; it < 8; ++it) {
        int flat = it * 512 + tid;            // 0..4095 float4 units
        int r = flat >> 6, q = flat & 63;
        reinterpret_cast<float4*>(&xtile[r][0])[q] =
            reinterpret_cast<const float4*>(x + (size_t)(rowBase + r) * DIM)[q];
    }
    __syncthreads();

    // ---- A fragments (fp8) packed from LDS: lane holds x[rg*16+lm][k32*32+lq*8+j] ----
    unsigned long long afr[4][8];
    #pragma unroll
    for (int rg = 0; rg < 4; ++rg) {
        const float* xr = &xtile[rg * 16 + lm][lq * 8];
        #pragma unroll
        for (int k32 = 0; k32 < 8; ++k32) {
            float4 u0 = *reinterpret_cast<const float4*>(xr + k32 * 32);
            float4 u1 = *reinterpret_cast<const float4*>(xr + k32 * 32 + 4);
            afr[rg][k32] = pack8fp8(u0, u1);
        }
    }

    // ---- B pipeline: 4 buffers, prefetch distance 3 ----
    unsigned long long bb[4][4];
    #pragma unroll
    for (int s = 0; s < 3; ++s) {
        const int k0 = s & 7;
        #pragma unroll
        for (int cf = 0; cf < 4; ++cf)
            bb[s & 3][cf] = whf64[((size_t)(k0 * 512 + wave16 + cf)) * 64 + lane];
    }

    for (int p = 0; p < 16; ++p) {               // 16 passes x 64 codes
        const int pbase16 = wave16 + p * 4;
        f32x4 acc[4][4];
        #pragma unroll
        for (int rg = 0; rg < 4; ++rg)
            #pragma unroll
            for (int cf = 0; cf < 4; ++cf)
                acc[rg][cf] = (f32x4){0.f, 0.f, 0.f, 0.f};

        #pragma unroll
        for (int k32 = 0; k32 < 8; ++k32) {
            const int s = p * 8 + k32;
            if (s + 3 < 128) {                   // prefetch step s+3
                const int s3k = (k32 + 3) & 7;
                const int p3 = p + ((k32 + 3) >> 3);
                #pragma unroll
                for (int cf = 0; cf < 4; ++cf)
                    bb[(k32 + 3) & 3][cf] = whf64[
                        ((size_t)(s3k * 512 + wave16 + p3 * 4 + cf)) * 64 + lane];
            }
            #pragma unroll
            for (int cf = 0; cf < 4; ++cf)
                #pragma unroll
                for (int rg = 0; rg < 4; ++rg)
                    acc[rg][cf] = __builtin_amdgcn_mfma_f32_16x16x32_fp8_fp8(
                        (long long)afr[rg][k32], (long long)bb[k32 & 3][cf],
                        acc[rg][cf], 0, 0, 0);
        }

        // ---- approx score: s = wsq - 2*dot = wsq - (2/8192)*acc_scaled ----
        float wq[4];
        #pragma unroll
        for (int cf = 0; cf < 4; ++cf)
            wq[cf] = wsq[(pbase16 + cf) * 16 + lm];

        float mloc[16];
        #pragma unroll
        for (int rg = 0; rg < 4; ++rg) {
            #pragma unroll
            for (int r = 0; r < 4; ++r) {
                float m = __builtin_huge_valf();
                #pragma unroll
                for (int cf = 0; cf < 4; ++cf)
                    m = fminf(m, fmaf(-2.0f / WSCALE, acc[rg][cf][r], wq[cf]));
                mloc[rg * 4 + r] = m;
                float rm = m;
                rm = fminf(rm, __shfl_xor(rm, 1, 64));
                rm = fminf(rm, __shfl_xor(rm, 2, 64));
                rm = fminf(rm, __shfl_xor(rm, 4, 64));
                rm = fminf(rm, __shfl_xor(rm, 8, 64));
                if (lm == 0)
                    atomicMin(&rowmin[rg * 16 + lq * 4 + r], f2ord(rm));
            }
        }
        // collect candidates vs prefix min (stale rowmin => superset; the
        // winner is ALWAYS collected: its own score is already in rowmin).
        // Overflowed candidates (pos>=CAP) are exact-rescored inline -> no drops.
        #pragma unroll
        for (int rg = 0; rg < 4; ++rg) {
            #pragma unroll
            for (int r = 0; r < 4; ++r) {
                const int row = rg * 16 + lq * 4 + r;
                float limit = ord2f(rowmin[row]) + MARGIN;
                if (mloc[rg * 4 + r] <= limit) {
                    #pragma unroll
                    for (int cf = 0; cf < 4; ++cf) {
                        float s = fmaf(-2.0f / WSCALE, acc[rg][cf][r], wq[cf]);
                        if (s <= limit) {
                            int c = (pbase16 + cf) * 16 + lm;
                            int pos = atomicAdd(&cnt[row], 1);
                            if (pos < CAP) {
                                candc[row][pos] = c;
                                cands[row][pos] = s;
                            } else {
                                rescore_one(&xtile[row][0], w, wsq,
                                            xsq[rowBase + row], rowBase + row,
                                            c, best64g);
                            }
                        }
                    }
                }
            }
        }
    }
    __syncthreads();

    // ---- final-margin prune + exact rescore of stored candidates ----
    for (int slot = tid; slot < BM * CAP; slot += 512) {
        int row = slot / CAP, pos = slot - (slot / CAP) * CAP;
        int n = cnt[row] < CAP ? cnt[row] : CAP;
        if (pos < n && cands[row][pos] <= ord2f(rowmin[row]) + MARGIN)
            rescore_one(&xtile[row][0], w, wsq, xsq[rowBase + row],
                        rowBase + row, candc[row][pos], best64g);
    }
}

// Final: read per-row best key, write index + gather codeword.
__global__ __launch_bounds__(256)
void out_kernel(const float* __restrict__ w,
                const unsigned long long* __restrict__ best64g,
                float* __restrict__ out_q, float* __restrict__ out_idx) {
    int r = blockIdx.x * 4 + (threadIdx.x >> 6);
    int lane = threadIdx.x & 63;
    unsigned long long key = best64g[r];
    int idx = (int)(key & 0xFFFFFFFFu) & (NCODES - 1);   // sanitize: no OOB faults
    float4 v = reinterpret_cast<const float4*>(w + (size_t)idx * DIM)[lane];
    reinterpret_cast<float4*>(out_q + (size_t)r * DIM)[lane] = v;
    if (lane == 0) out_idx[r] = (float)idx;
}

extern "C" void kernel_launch(void* const* d_in, const int* in_sizes, int n_in,
                              void* d_out, int out_size, void* d_ws, size_t ws_size,
                              hipStream_t stream) {
    const float* x = (const float*)d_in[0];   // (16384, 256) fp32
    const float* w = (const float*)d_in[1];   // (8192, 256) fp32
    float* out_q = (float*)d_out;
    float* out_idx = (float*)d_out + (size_t)NROWS * DIM;

    unsigned long long* whf64 = (unsigned long long*)d_ws;            // 2 MB fp8 frags
    float* wsq = (float*)((char*)d_ws + (size_t)NCODES * DIM);        // 32 KB
    float* xsq = wsq + NCODES;                                        // 64 KB
    unsigned long long* best64g = (unsigned long long*)(xsq + NROWS); // 128 KB

    int prep_units = WFRAG_UNITS + NROWS + NCODES;
    prep_kernel<<<(prep_units + 255) / 256, 256, 0, stream>>>(
        x, w, whf64, xsq, wsq, best64g);
    vq_main<<<NROWS / BM, 512, 0, stream>>>(x, w, whf64, wsq, xsq, best64g);
    out_kernel<<<NROWS / 4, 256, 0, stream>>>(w, best64g, out_q, out_idx);
}